// Round 2
// baseline (167.594 us; speedup 1.0000x reference)
//
#include <hip/hip_runtime.h>
#include <cstddef>

// B=16, h=8, Ch=32, H=W=56, N=3136
//   heads 0-1 -> 3x3 (w3,b3), cbase hh*32
//   heads 2-4 -> 5x5 (w5,b5), cbase hh*32-64
//   heads 5-7 -> 7x7 (w7,b7), cbase hh*32-160
// out[b][n][hh*32+ch] = q[b][hh][n][ch] * dwconv(v)[b][hh][n][ch]
//
// R7: LDS data path DELETED. R6 proved occupancy isn't the lever (23->31%
// occ, flat time): the per-dy chain vmcnt(0) -> ds_write -> lgkmcnt ->
// ds_read serialized every iteration (~215 b128 LDS ops/wave ~= 55% of the
// CU cycle budget). Now the conv window is read straight from global as
// NR overlapping buffer loads per dy (L1/L2-resident row, K-fold reuse),
// feeding FMAs directly; loads pipeline across dy. x-OOB handled by
// pre-clamped per-lane offsets + buffer bounds check (returns 0);
// y-OOB by num_records=0 (proven R2-R4). LDS holds only weights (6.3 KB).

#define BH 16
#define NH 8
#define CH 32
#define HW 56
#define NN (HW*HW)
#define ROWB (HW*CH*4)          // 7168 B per image row

typedef float f32x4 __attribute__((ext_vector_type(4)));
typedef unsigned int u32x4 __attribute__((ext_vector_type(4)));

__device__ __forceinline__ f32x4 bload(__amdgpu_buffer_rsrc_t rs, int voff) {
    u32x4 u = __builtin_amdgcn_raw_buffer_load_b128(rs, voff, 0, 0);
    f32x4 f; __builtin_memcpy(&f, &u, 16); return f;
}

template<int K>
__device__ __forceinline__ void run_head(
    const float* __restrict__ q, const float* __restrict__ v,
    const float* __restrict__ w, const float* __restrict__ bias,
    float* __restrict__ out, int b, int hh, int y0, int cbase,
    float* __restrict__ w_lds)
{
    constexpr int P = K / 2;
    constexpr int NR = 7 + K - 1;       // window width in px per output strip
    const int t = threadIdx.x;

    // Stage weights into LDS, layout [tap][c].
    const int nw = K * K * CH;
    for (int i = t; i < nw; i += 256) {
        int tap = i >> 5, c = i & 31;
        w_lds[tap * CH + c] = w[(cbase + c) * (K * K) + tap];
    }
    __syncthreads();                    // only barrier in the kernel

    const int wid  = t >> 6;            // wave id = row within 4-row group
    const int lane = t & 63;
    const int y    = y0 + wid;
    const int xseg = lane >> 3;         // 8 x-strips of 7 px
    const int chq  = lane & 7;          // 8 ch-quads
    const int x0   = xseg * 7;
    const int ch   = chq * 4;

    const size_t plane = ((size_t)b * NH + hh) * (size_t)NN * CH;
    const float* vb   = v + plane;
    const float* qrow = q + plane + (size_t)y * (HW * CH);

    // Per-lane x-window byte offsets, clamped: OOB px -> huge offset ->
    // buffer bounds check returns 0. Computed ONCE (x-window is dy-invariant).
    // Clamp result is an opaque non-negative VGPR: no negative-voffset or
    // imm-folding hazards in the MUBUF bounds math.
    int vx[NR];
#pragma unroll
    for (int j = 0; j < NR; ++j) {
        const int px = x0 - P + j;
        vx[j] = ((unsigned)px < (unsigned)HW) ? (px * CH + ch) * 4 : 0x40000000;
    }

    const f32x4 bias4 = *(const f32x4*)(bias + cbase + ch);
    f32x4 acc[7];
#pragma unroll
    for (int i = 0; i < 7; ++i) acc[i] = bias4;

#pragma unroll
    for (int dy = 0; dy < K; ++dy) {
        const int yy = y + dy - P;
        const bool ok = (unsigned)yy < (unsigned)HW;
        const float* base = vb + (ptrdiff_t)yy * (HW * CH);
        // OOB row -> num_records=0 -> loads return 0 (y zero-padding)
        __amdgpu_buffer_rsrc_t rs = __builtin_amdgcn_make_buffer_rsrc(
            (void*)base, (short)0, ok ? ROWB : 0, 0x00020000);

        // Overlapping window loads straight from global (L1/L2-resident).
        f32x4 r[NR];
#pragma unroll
        for (int j = 0; j < NR; ++j) r[j] = bload(rs, vx[j]);

#pragma unroll
        for (int dx = 0; dx < K; ++dx) {
            const f32x4 w4 = *(const f32x4*)(w_lds + (dy * K + dx) * CH + ch);
#pragma unroll
            for (int i = 0; i < 7; ++i)
                acc[i] += r[i + dx] * w4;
        }
    }

    // Epilogue: q load + out store directly in the conv lane mapping
    // (8 x 128 B segments per instruction — coalesced enough, no LDS park).
    float* obase = out + ((size_t)b * NN + (size_t)y * HW) * (NH * CH) + hh * CH + ch;
#pragma unroll
    for (int i = 0; i < 7; ++i) {
        const int px = x0 + i;
        const f32x4 q4 = *(const f32x4*)(qrow + (size_t)px * CH + ch);
        *(f32x4*)(obase + (size_t)px * (NH * CH)) = acc[i] * q4;
    }
}

__global__ __launch_bounds__(256, 4)   // 128 VGPR cap; LDS only 6.3 KB now
void clusterformer_fused(const float* __restrict__ q, const float* __restrict__ v,
                         const float* __restrict__ w3, const float* __restrict__ b3,
                         const float* __restrict__ w5, const float* __restrict__ b5,
                         const float* __restrict__ w7, const float* __restrict__ b7,
                         float* __restrict__ out)
{
    __shared__ __align__(16) float w_lds[49 * CH];       // 6272 B

    // bid -> (plane p, ygroup): XCD-local planes (R3: FETCH 75->53 MB) and
    // heavy heads (K7) first for tail balance.
    const int bid  = blockIdx.x;
    const int p_lo = bid & 7;
    const int t2   = bid >> 3;         // 0..223
    const int p_hi = t2 / 14;
    const int yg   = t2 % 14;
    const int p    = p_hi * 8 + p_lo;  // 0..127
    const int b    = p & 15;
    const int hhp  = p >> 4;           // dispatch-ordered head
    const int hh   = (hhp < 3) ? (5 + hhp) : ((hhp < 6) ? (hhp - 1) : (hhp - 6));
    const int y0   = yg * 4;

    if (hh < 2)      run_head<3>(q, v, w3, b3, out, b, hh, y0, hh * 32,       w_lds);
    else if (hh < 5) run_head<5>(q, v, w5, b5, out, b, hh, y0, hh * 32 - 64,  w_lds);
    else             run_head<7>(q, v, w7, b7, out, b, hh, y0, hh * 32 - 160, w_lds);
}

extern "C" void kernel_launch(void* const* d_in, const int* in_sizes, int n_in,
                              void* d_out, int out_size, void* d_ws, size_t ws_size,
                              hipStream_t stream) {
    const float* q  = (const float*)d_in[0];
    const float* v  = (const float*)d_in[1];
    const float* w3 = (const float*)d_in[2];
    const float* b3 = (const float*)d_in[3];
    const float* w5 = (const float*)d_in[4];
    const float* b5 = (const float*)d_in[5];
    const float* w7 = (const float*)d_in[6];
    const float* b7 = (const float*)d_in[7];
    float* out = (float*)d_out;

    const int grid = BH * NH * 14;     // 1792 blocks of 256 threads
    clusterformer_fused<<<grid, 256, 0, stream>>>(q, v, w3, b3, w5, b5, w7, b7, out);
}

// Round 3
// 161.772 us; speedup vs baseline: 1.0360x; 1.0360x over previous
//
#include <hip/hip_runtime.h>
#include <cstddef>

// B=16, h=8, Ch=32, H=W=56, N=3136
//   heads 0-1 -> 3x3 (w3,b3), cbase hh*32
//   heads 2-4 -> 5x5 (w5,b5), cbase hh*32-64
//   heads 5-7 -> 7x7 (w7,b7), cbase hh*32-160
// out[b][n][hh*32+ch] = q[b][hh][n][ch] * dwconv(v)[b][hh][n][ch]
//
// R8: block-cooperative row staging. R6 (occupancy null) + R7 (more VMEM =
// slower) => binder is VMEM request pressure. Previously each block issued
// 4*K global row-reads for 4+2P distinct v rows (4x redundancy at K=7).
// Now: stage the 4+2P rows ONCE into shared LDS (one barrier), conv runs
// entirely from LDS, no per-dy vmcnt chains. v L1-miss traffic drops 2.8x.
// LDS row layout: stride 58 px, 2-px zero gaps between rows serve as x-pads
// (full pads for K<=5; K=7's outermost +-3px via 2 lane masks). 81.0 KB LDS
// -> 2 blocks/CU; per-XCD working set ~3.7MB ~= L2, stage loads L2-hit.

#define BH 16
#define NH 8
#define CH 32
#define HW 56
#define NN (HW*HW)
#define ROWB (HW*CH*4)          // 7168 B per image row
#define RS 58                   // LDS row stride in px (56 + 2 gap)
#define BUF_PX 584              // 3 (lead pad) + 10*58 + 1 (trail) for K=7
#define BUF_FLOATS (BUF_PX*CH)  // 18688 floats = 74752 B

typedef float f32x4 __attribute__((ext_vector_type(4)));
typedef unsigned int u32x4 __attribute__((ext_vector_type(4)));

__device__ __forceinline__ f32x4 bload(__amdgpu_buffer_rsrc_t rs, int voff) {
    u32x4 u = __builtin_amdgcn_raw_buffer_load_b128(rs, voff, 0, 0);
    f32x4 f; __builtin_memcpy(&f, &u, 16); return f;
}

template<int K>
__device__ __forceinline__ void run_head(
    const float* __restrict__ q, const float* __restrict__ v,
    const float* __restrict__ w, const float* __restrict__ bias,
    float* __restrict__ out, int b, int hh, int y0, int cbase,
    float* __restrict__ w_lds, float* __restrict__ bufs)
{
    constexpr int P = K / 2;
    constexpr int NR = 7 + K - 1;       // window width in px per 7-px strip
    constexpr int NROWS = 4 + 2 * P;    // rows staged per block
    const int t = threadIdx.x;

    // Stage weights into LDS, layout [tap][c].
    const int nw = K * K * CH;
    for (int i = t; i < nw; i += 256) {
        int tap = i >> 5, c = i & 31;
        w_lds[tap * CH + c] = w[(cbase + c) * (K * K) + tap];
    }

    // Zero the pad px: leading P, 2-px gap after each row, 1 trailing.
    // Row rr lives at px L = P + rr*RS + px, px in [0,56). A window read at
    // px -2..-1 / 56..57 lands in a gap (zero); K=7's px -3 / +58 are the
    // only out-of-gap reads, masked below.
    {
        f32x4 z = {0.f, 0.f, 0.f, 0.f};
        const int NG = P + 2 * NROWS + 1;
        if (t < NG * 8) {
            const int g = t >> 3, sub = t & 7;
            int px;
            if (g < P) px = g;
            else if (g < P + 2 * NROWS) {
                const int rr = (g - P) >> 1;
                px = P + rr * RS + 56 + ((g - P) & 1);
            } else px = P + NROWS * RS;
            *(f32x4*)(bufs + px * CH + sub * 4) = z;
        }
    }

    const int wid  = t >> 6;            // wave id = output row within block
    const int lane = t & 63;
    const int y    = y0 + wid;
    const int xseg = lane >> 3;         // 8 x-strips of 7 px
    const int chq  = lane & 7;          // 8 ch-quads
    const int x0   = xseg * 7;
    const int ch   = chq * 4;

    const size_t plane = ((size_t)b * NH + hh) * (size_t)NN * CH;
    const float* vb   = v + plane;
    const float* qrow = q + plane + (size_t)y * (HW * CH);

    // q prefetch in the conv lane mapping; consumed in the epilogue.
    f32x4 qf[7];
#pragma unroll
    for (int i = 0; i < 7; ++i)
        qf[i] = *(const f32x4*)(qrow + (size_t)(x0 + i) * CH + ch);

    // Cooperative staging: wave wid stages rows wid, wid+4, ... Each row is
    // 7 contiguous 1-KB wave loads. OOB rows: num_records=0 -> zeros (proven
    // R2-R4), which is exactly the y zero-padding.
    for (int rr = wid; rr < NROWS; rr += 4) {
        const int yy = y0 - P + rr;
        const bool ok = (unsigned)yy < (unsigned)HW;
        __amdgpu_buffer_rsrc_t rs = __builtin_amdgcn_make_buffer_rsrc(
            (void*)(vb + (ptrdiff_t)yy * (HW * CH)), (short)0, ok ? ROWB : 0, 0x00020000);
        f32x4 ld[7];
#pragma unroll
        for (int k = 0; k < 7; ++k) ld[k] = bload(rs, k * 1024 + lane * 16);
        float* dst = bufs + (size_t)(P + rr * RS) * CH;
#pragma unroll
        for (int k = 0; k < 7; ++k)
            *(f32x4*)(dst + k * 256 + lane * 4) = ld[k];
    }
    __syncthreads();                    // only barrier in the kernel

    // K=7 edge masks: px -3 reads prev row's px55, px +58 reads next row's
    // px0 (real data, must be zero). Only xseg 0 / 7 are affected.
    const float mL = (xseg == 0) ? 0.f : 1.f;
    const float mR = (xseg == 7) ? 0.f : 1.f;

    const f32x4 bias4 = *(const f32x4*)(bias + cbase + ch);
    f32x4 acc[7];
#pragma unroll
    for (int i = 0; i < 7; ++i) acc[i] = bias4;

#pragma unroll
    for (int dy = 0; dy < K; ++dy) {
        const int rr = wid + dy;        // LDS row index (global row y+dy-P)
        // window px x0-P+j -> LDS px rr*RS + x0 + j (lead pad P cancels)
        const float* rb = bufs + (size_t)(rr * RS + x0) * CH + ch;
        f32x4 r[NR];
#pragma unroll
        for (int j = 0; j < NR; ++j)
            r[j] = *(const f32x4*)(rb + j * CH);
        if constexpr (K == 7) { r[0] *= mL; r[NR - 1] *= mR; }

#pragma unroll
        for (int dx = 0; dx < K; ++dx) {
            const f32x4 w4 = *(const f32x4*)(w_lds + (dy * K + dx) * CH + ch);
#pragma unroll
            for (int i = 0; i < 7; ++i)
                acc[i] += r[i + dx] * w4;
        }
    }

    // Epilogue: direct multiply+store in the conv lane mapping
    // (8 x 128 B segments per instruction, 16 cache lines — same line count
    // as a contiguous 1-KB burst).
    float* obase = out + ((size_t)b * NN + (size_t)y * HW) * (NH * CH) + hh * CH + ch;
#pragma unroll
    for (int i = 0; i < 7; ++i)
        *(f32x4*)(obase + (size_t)(x0 + i) * (NH * CH)) = acc[i] * qf[i];
}

__global__ __launch_bounds__(256, 2)   // 81.0 KB LDS -> 2 blocks/CU
void clusterformer_fused(const float* __restrict__ q, const float* __restrict__ v,
                         const float* __restrict__ w3, const float* __restrict__ b3,
                         const float* __restrict__ w5, const float* __restrict__ b5,
                         const float* __restrict__ w7, const float* __restrict__ b7,
                         float* __restrict__ out)
{
    __shared__ __align__(16) float bufs[BUF_FLOATS];   // 74752 B
    __shared__ __align__(16) float w_lds[49 * CH];     // 6272 B

    // bid -> (plane p, ygroup): XCD-local planes (R3: FETCH 75->53 MB) and
    // heavy heads (K7) first for tail balance.
    const int bid  = blockIdx.x;
    const int p_lo = bid & 7;
    const int t2   = bid >> 3;         // 0..223
    const int p_hi = t2 / 14;
    const int yg   = t2 % 14;
    const int p    = p_hi * 8 + p_lo;  // 0..127
    const int b    = p & 15;
    const int hhp  = p >> 4;           // dispatch-ordered head
    const int hh   = (hhp < 3) ? (5 + hhp) : ((hhp < 6) ? (hhp - 1) : (hhp - 6));
    const int y0   = yg * 4;

    if (hh < 2)      run_head<3>(q, v, w3, b3, out, b, hh, y0, hh * 32,       w_lds, bufs);
    else if (hh < 5) run_head<5>(q, v, w5, b5, out, b, hh, y0, hh * 32 - 64,  w_lds, bufs);
    else             run_head<7>(q, v, w7, b7, out, b, hh, y0, hh * 32 - 160, w_lds, bufs);
}

extern "C" void kernel_launch(void* const* d_in, const int* in_sizes, int n_in,
                              void* d_out, int out_size, void* d_ws, size_t ws_size,
                              hipStream_t stream) {
    const float* q  = (const float*)d_in[0];
    const float* v  = (const float*)d_in[1];
    const float* w3 = (const float*)d_in[2];
    const float* b3 = (const float*)d_in[3];
    const float* w5 = (const float*)d_in[4];
    const float* b5 = (const float*)d_in[5];
    const float* w7 = (const float*)d_in[6];
    const float* b7 = (const float*)d_in[7];
    float* out = (float*)d_out;

    const int grid = BH * NH * 14;     // 1792 blocks of 256 threads
    clusterformer_fused<<<grid, 256, 0, stream>>>(q, v, w3, b3, w5, b5, w7, b7, out);
}